// Round 1
// baseline (343.709 us; speedup 1.0000x reference)
//
#include <hip/hip_runtime.h>

// Depthwise 3x3 conv, pad=1, stride=1, single shared 3x3 kernel across all
// B*C=1024 planes of 224x224 fp32. Memory-bound: ~411 MB min HBM traffic.
// Each thread computes a 4x4 output tile (4 rows x float4) for vertical
// register reuse; halo overlap is absorbed by L1/L2.

#define HH 224
#define WW 224
#define X4T 56   // WW/4 float4 tiles per row
#define Y4T 56   // HH/4 row-blocks

__global__ __launch_bounds__(256) void dwconv3x3_shared_w(
    const float* __restrict__ X, const float* __restrict__ Wk,
    float* __restrict__ Out, int nTiles)
{
    int idx = blockIdx.x * 256 + threadIdx.x;
    if (idx >= nTiles) return;

    int x4 = idx % X4T;
    int t  = idx / X4T;
    int y4 = t % Y4T;
    int p  = t / Y4T;

    // 9 shared weights — one cache line, L1 broadcast across all threads.
    const float w00 = Wk[0], w01 = Wk[1], w02 = Wk[2];
    const float w10 = Wk[3], w11 = Wk[4], w12 = Wk[5];
    const float w20 = Wk[6], w21 = Wk[7], w22 = Wk[8];

    const int x0 = x4 * 4;
    const int y0 = y4 * 4;
    const float* plane  = X   + (size_t)p * (HH * WW);
    float*       oplane = Out + (size_t)p * (HH * WW);

    // 6 input rows x 6 columns (left halo, 4 main, right halo), in registers.
    float row[6][6];
    #pragma unroll
    for (int r = 0; r < 6; ++r) {
        const int yr = y0 - 1 + r;
        const bool yok = (yr >= 0) && (yr < HH);
        const float* rp = plane + yr * WW + x0;
        float4 v = yok ? *(const float4*)rp : make_float4(0.f, 0.f, 0.f, 0.f);
        row[r][0] = (yok && x0 > 0)      ? rp[-1] : 0.f;
        row[r][1] = v.x;
        row[r][2] = v.y;
        row[r][3] = v.z;
        row[r][4] = v.w;
        row[r][5] = (yok && x0 + 4 < WW) ? rp[4]  : 0.f;
    }

    #pragma unroll
    for (int j = 0; j < 4; ++j) {
        float4 o;
        float* op = (float*)&o;
        #pragma unroll
        for (int c = 0; c < 4; ++c) {
            float acc;
            acc  = w00 * row[j + 0][c + 0] + w01 * row[j + 0][c + 1] + w02 * row[j + 0][c + 2];
            acc += w10 * row[j + 1][c + 0] + w11 * row[j + 1][c + 1] + w12 * row[j + 1][c + 2];
            acc += w20 * row[j + 2][c + 0] + w21 * row[j + 2][c + 1] + w22 * row[j + 2][c + 2];
            op[c] = acc;
        }
        *(float4*)(oplane + (y0 + j) * WW + x0) = o;
    }
}

extern "C" void kernel_launch(void* const* d_in, const int* in_sizes, int n_in,
                              void* d_out, int out_size, void* d_ws, size_t ws_size,
                              hipStream_t stream) {
    const float* X  = (const float*)d_in[0];
    const float* Wk = (const float*)d_in[1];
    float* Out = (float*)d_out;

    const int nPlanes = 16 * 64;                 // B*C
    const int nTiles  = nPlanes * X4T * Y4T;     // 3,211,264
    const int threads = 256;
    const int blocks  = (nTiles + threads - 1) / threads;  // 12,544

    dwconv3x3_shared_w<<<blocks, threads, 0, stream>>>(X, Wk, Out, nTiles);
}